// Round 6
// baseline (195.139 us; speedup 1.0000x reference)
//
#include <hip/hip_runtime.h>

#define NN 50000
#define SNEI 16
#define GB 782            // ceil(50000/64)

typedef unsigned short ushort_t;
typedef unsigned int uint_t;
typedef unsigned long long u64;
typedef __attribute__((ext_vector_type(8))) short bhalf8;
typedef __attribute__((ext_vector_type(4))) float facc4;

__device__ __forceinline__ float b2f(uint_t u) {
    union { uint_t u; float f; } x; x.u = u << 16; return x.f;
}
__device__ __forceinline__ ushort_t f2b(float f) {
    union { float f; uint_t u; } x; x.f = f;
    return (ushort_t)((x.u + 0x7FFFu + ((x.u >> 16) & 1u)) >> 16);
}
__device__ __forceinline__ u64 pack4(float a, float b, float c, float d) {
    return (u64)f2b(a) | ((u64)f2b(b) << 16) | ((u64)f2b(c) << 32) | ((u64)f2b(d) << 48);
}

typedef const __attribute__((address_space(1))) void cglb_t;
typedef __attribute__((address_space(3))) void lds3_t;
__device__ __forceinline__ void gload16(const void* g, void* l) {
    __builtin_amdgcn_global_load_lds((cglb_t*)g, (lds3_t*)l, 16, 0, 0);
}

// ---------------------------------------------------------------------------
// One-time weight setup. Fragment k-bijection: chunk (ks*8+nf)*64+lane,
// elem j of lane l holds W[k][c] with k = ks*32 + (l>>4)*8 + j (16B-contig),
// c = nf*16 + (l&15). Same bijection used by all A-staging paths.
// Layer-1 weights are pre-multiplied by prepW: W'1 = prepW @ W1  [256,128].
// perm layout (chunks): [L1: mp0{x 4096|n 4096} mp1{...}][L2: same] = 32768.
// ---------------------------------------------------------------------------
__global__ void permSetup(const float* __restrict__ prepW,
                          const float* __restrict__ Wx1, const float* __restrict__ Wn1,
                          const float* __restrict__ Wx2, const float* __restrict__ Wn2,
                          ushort_t* __restrict__ dst)
{
    int e = blockIdx.x * 256 + threadIdx.x;
    int q8 = e >> 3, j = e & 7;
    int layer = q8 >> 14;
    int qq = q8 & 16383;
    int mp = qq >> 13, isN = (qq >> 12) & 1, q = qq & 4095;
    int lane = q & 63, nf = (q >> 6) & 7, ks = q >> 9;
    int c = nf * 16 + (lane & 15);                 // [0,128)
    int k = ks * 32 + ((lane >> 4) << 3) + j;      // [0,256)
    float v;
    if (layer == 0) {
        const float* W1 = (isN ? Wn1 : Wx1) + mp * 16384 + (c >> 6) * 8192 + (c & 63);
        const float* pw = prepW + (size_t)k * 128;
        float s0 = 0.f, s1 = 0.f;
#pragma unroll 4
        for (int p = 0; p < 128; p += 2) {
            s0 += pw[p]     * W1[(size_t)p * 64];
            s1 += pw[p + 1] * W1[(size_t)(p + 1) * 64];
        }
        v = s0 + s1;
    } else {
        const float* W2 = (isN ? Wn2 : Wx2) + mp * 32768 + (c >> 6) * 16384 + (size_t)k * 64 + (c & 63);
        v = *W2;
    }
    dst[(size_t)q8 * 8 + j] = f2b(v);
}

// ---------------------------------------------------------------------------
// Dual-projection GEMM, K=256 always. wave_n=0: Xh = X@Wx -> relu -> fp32 out
// (head-interleaved x-slots at obase), optionally bf16 h1 x-part (L1).
// wave_n=1: P = X@Wn -> bf16 P in SLICED layout (NO relu; mean+relu in gather):
//   P[slice][node][32cols], slice = cpr>>5 (sub-table NN*64B, L2-resident).
// XF32: X fp32 (feats, converted during staging); else bf16 via gload_lds.
// Tile 64 rows x 128 cols/role, BK=64, 4 waves, 40KB LDS, 4 blocks/CU.
// LDS chunks: X [0,512) | Wx [512,1536) | Wn [1536,2560).
// ---------------------------------------------------------------------------
template<bool XF32, bool L1>
__global__ __launch_bounds__(256, 4)
void proj_gemm(const void* __restrict__ Xv, size_t xStr,
               const ushort_t* __restrict__ W, size_t wStr,
               float* __restrict__ out, size_t oStr,
               ushort_t* __restrict__ h1, size_t hStr,
               ushort_t* __restrict__ P, size_t PStr)
{
    __shared__ bhalf8 lds[2560];
    u64* l64 = (u64*)lds;
    const int tid = threadIdx.x;
    const int lane = tid & 63;
    const int wid = tid >> 6;
    const int wave_m = wid >> 1, wave_n = wid & 1;
    const int m0 = blockIdx.x * 64;
    const int mp = blockIdx.y;

    const ushort_t* wx = W + (size_t)mp * wStr;
    const ushort_t* wn = wx + 4096 * 8;
    const float*    Xf = (const float*)Xv    + (size_t)mp * xStr;
    const ushort_t* Xb = (const ushort_t*)Xv + (size_t)mp * xStr;
    float* outp = out + (size_t)mp * oStr;
    ushort_t* h1p = L1 ? (h1 + (size_t)mp * hStr) : nullptr;
    ushort_t* Pp  = P + (size_t)mp * PStr;

    facc4 acc[2][8];
    const facc4 z = {0.f, 0.f, 0.f, 0.f};
#pragma unroll
    for (int i = 0; i < 2; ++i)
#pragma unroll
        for (int j = 0; j < 8; ++j) acc[i][j] = z;

    for (int kt = 0; kt < 4; ++kt) {
        // ---- X stage: frag chunk s holds rows m0+mf*16+(s&15), k-slice ----
        if constexpr (XF32) {
#pragma unroll
            for (int it = 0; it < 2; ++it) {
                int s = tid + it * 256;              // [0,512)
                int fp = s >> 6, ls = s & 63;
                int mf = fp & 3, ksl = fp >> 2;
                int grow = m0 + mf * 16 + (ls & 15); if (grow > NN - 1) grow = NN - 1;
                const float* gp = Xf + (size_t)grow * 256 + kt * 64 + ksl * 32 + ((ls >> 4) << 3);
                float4 f0 = *(const float4*)gp, f1 = *(const float4*)(gp + 4);
                l64[s * 2]     = pack4(f0.x, f0.y, f0.z, f0.w);
                l64[s * 2 + 1] = pack4(f1.x, f1.y, f1.z, f1.w);
            }
        } else {
#pragma unroll
            for (int it = 0; it < 2; ++it) {
                int u = wid + it * 4;                // fragpos 0..7
                int mf = u & 3, ksl = u >> 2;
                int grow = m0 + mf * 16 + (lane & 15); if (grow > NN - 1) grow = NN - 1;
                const ushort_t* src = Xb + (size_t)grow * 256 + kt * 64 + ksl * 32 + ((lane >> 4) << 3);
                gload16(src, (char*)lds + (u * 64 + lane) * 16);
            }
        }
        // ---- W stage: linear gload_lds of pre-permuted chunks ----
#pragma unroll
        for (int it = 0; it < 4; ++it) {
            int cb = (it * 4 + wid) * 64;            // [0,1024)
            gload16(wx + ((size_t)kt * 1024 + cb + lane) * 8,
                    (char*)lds + (512 + cb + lane) * 16);
            gload16(wn + ((size_t)kt * 1024 + cb + lane) * 8,
                    (char*)lds + (1536 + cb + lane) * 16);
        }
        __syncthreads();
        // ---- compute ----
        const int wB = wave_n ? 1536 : 512;
#pragma unroll
        for (int ksl = 0; ksl < 2; ++ksl) {
            bhalf8 a0 = lds[(ksl * 4 + wave_m * 2 + 0) * 64 + lane];
            bhalf8 a1 = lds[(ksl * 4 + wave_m * 2 + 1) * 64 + lane];
#pragma unroll
            for (int nf = 0; nf < 8; ++nf) {
                bhalf8 b = lds[wB + (ksl * 8 + nf) * 64 + lane];
                acc[0][nf] = __builtin_amdgcn_mfma_f32_16x16x32_bf16(a0, b, acc[0][nf], 0, 0, 0);
                acc[1][nf] = __builtin_amdgcn_mfma_f32_16x16x32_bf16(a1, b, acc[1][nf], 0, 0, 0);
            }
        }
        __syncthreads();
    }
    // ---- epilogue: D map col=lane&15, row=(lane>>4)*4+reg ----
    const int cl = lane & 15, rg = lane >> 4;
    const int obase = L1 ? 0 : 256;
#pragma unroll
    for (int mf2 = 0; mf2 < 2; ++mf2) {
        int rowb = m0 + (wave_m * 2 + mf2) * 16 + rg * 4;
#pragma unroll
        for (int nf = 0; nf < 8; ++nf) {
            int cpr = nf * 16 + cl;                  // [0,128)
            int icol = (cpr >> 6) * 128 + (cpr & 63);
            facc4 v = acc[mf2][nf];
#pragma unroll
            for (int rr = 0; rr < 4; ++rr) {
                int row = rowb + rr;
                if (row < NN) {
                    if (wave_n == 0) {
                        float f = fmaxf(v[rr], 0.0f);
                        outp[(size_t)row * 512 + obase + icol] = f;
                        if constexpr (L1)
                            h1p[(size_t)row * 256 + icol] = f2b(f);
                    } else {
                        Pp[(size_t)(cpr >> 5) * (NN * 32) + (size_t)row * 32 + (cpr & 31)] = f2b(v[rr]);
                    }
                }
            }
        }
    }
}

// ---------------------------------------------------------------------------
// Sliced gather + mean + relu. Grid (782, slice=4, mp). Each (mp,slice) phase
// reads one contiguous NN*64B = 3.2MB sub-table -> L2-resident.
// Block = 64 nodes x 4 chunk-lanes; indices staged in LDS.
// Writes final n-slots of out (fp32) and, for L1, h1 n-part (bf16).
// ---------------------------------------------------------------------------
template<bool L1>
__global__ __launch_bounds__(256)
void gatherS(const ushort_t* __restrict__ P, size_t PStr,
             const int* __restrict__ nb, size_t nStr,
             float* __restrict__ out, size_t oStr,
             ushort_t* __restrict__ h1, size_t hStr)
{
    const int slice = blockIdx.y;                  // 0..3
    const int mp = blockIdx.z;
    const ushort_t* Pp = P + (size_t)mp * PStr + (size_t)slice * (NN * 32);
    const int* nbp = nb + (size_t)mp * nStr;
    float* outp = out + (size_t)mp * oStr;

    __shared__ int nls[1024];
    const int nodeBase = blockIdx.x * 64;
    {
        int i4 = nodeBase * 4 + threadIdx.x;       // int4 index into neigh
        int mx = NN * 4 - 1;
        if (i4 > mx) i4 = mx;
        ((int4*)nls)[threadIdx.x] = ((const int4*)nbp)[i4];
    }
    __syncthreads();

    const int nl = threadIdx.x >> 2, q = threadIdx.x & 3;
    const int node = nodeBase + nl;
    if (node >= NN) return;
    const int* nr = nls + nl * SNEI;
    float a0=0.f,a1=0.f,a2=0.f,a3=0.f,a4=0.f,a5=0.f,a6=0.f,a7=0.f;
#pragma unroll
    for (int s = 0; s < SNEI; ++s) {
        uint4 v = *(const uint4*)(Pp + (size_t)nr[s] * 32 + q * 8);
        a0 += b2f(v.x & 0xFFFFu); a1 += b2f(v.x >> 16);
        a2 += b2f(v.y & 0xFFFFu); a3 += b2f(v.y >> 16);
        a4 += b2f(v.z & 0xFFFFu); a5 += b2f(v.z >> 16);
        a6 += b2f(v.w & 0xFFFFu); a7 += b2f(v.w >> 16);
    }
    const float M = 0.0625f;
    float r0 = fmaxf(a0*M, 0.f), r1 = fmaxf(a1*M, 0.f);
    float r2 = fmaxf(a2*M, 0.f), r3 = fmaxf(a3*M, 0.f);
    float r4 = fmaxf(a4*M, 0.f), r5 = fmaxf(a5*M, 0.f);
    float r6 = fmaxf(a6*M, 0.f), r7 = fmaxf(a7*M, 0.f);
    const int head = slice >> 1;
    const int coff = head * 128 + 64 + (slice & 1) * 32 + q * 8;
    const int obase = L1 ? 0 : 256;
    float* o = outp + (size_t)node * 512 + obase + coff;
    *(float4*)o       = make_float4(r0, r1, r2, r3);
    *(float4*)(o + 4) = make_float4(r4, r5, r6, r7);
    if constexpr (L1) {
        ushort_t* hp = h1 + (size_t)mp * hStr + (size_t)node * 256 + coff;
        *(u64*)hp       = pack4(r0, r1, r2, r3);
        *(u64*)(hp + 4) = pack4(r4, r5, r6, r7);
    }
}

// ---------------------------------------------------------------------------
extern "C" void kernel_launch(void* const* d_in, const int* in_sizes, int n_in,
                              void* d_out, int out_size, void* d_ws, size_t ws_size,
                              hipStream_t stream)
{
    const float* feats  = (const float*)d_in[0];
    const float* prepWp = (const float*)d_in[1];
    const float* Wx1    = (const float*)d_in[2];
    const float* Wn1    = (const float*)d_in[3];
    const float* Wx2    = (const float*)d_in[4];
    const float* Wn2    = (const float*)d_in[5];
    const int*   neigh  = (const int*)d_in[6];
    float* out = (float*)d_out;
    ushort_t* ws = (ushort_t*)d_ws;

    const size_t permElems = 262144;                       // 512 KB
    const size_t needBatched = permElems * 2
        + 2 * ((size_t)NN * 128 * 2 + (size_t)NN * 256 * 2);  // 77.3 MB
    const bool batched = ws_size >= needBatched;
    const int nmp = batched ? 2 : 1;

    ushort_t* perm = ws;
    ushort_t* P    = ws + permElems;                        // nmp * NN*128
    ushort_t* h1   = P + (size_t)nmp * NN * 128;            // nmp * NN*256

    permSetup<<<1024, 256, 0, stream>>>(prepWp, Wx1, Wn1, Wx2, Wn2, perm);

    const size_t PStr = batched ? (size_t)NN * 128 : 0;
    const size_t hStr = batched ? (size_t)NN * 256 : 0;
    const size_t oStr = batched ? (size_t)NN * 512 : 0;
    const size_t nStr = batched ? (size_t)NN * SNEI : 0;
    const size_t wStr = batched ? (size_t)8192 * 8 : 0;
    const int passes = batched ? 1 : 2;

    for (int p = 0; p < passes; ++p) {
        const ushort_t* w1 = perm + (size_t)p * 8192 * 8;
        const ushort_t* w2 = perm + (size_t)(16384 + p * 8192) * 8;
        float* outp = out + (size_t)p * NN * 512;
        const int* nbp = neigh + (size_t)p * NN * SNEI;
        dim3 gp(GB, nmp), gg(GB, 4, nmp);

        proj_gemm<true, true><<<gp, 256, 0, stream>>>(
            feats, 0, w1, wStr, outp, oStr, h1, hStr, P, PStr);
        gatherS<true><<<gg, 256, 0, stream>>>(
            P, PStr, nbp, nStr, outp, oStr, h1, hStr);
        proj_gemm<false, false><<<gp, 256, 0, stream>>>(
            h1, hStr, w2, wStr, outp, oStr, nullptr, 0, P, PStr);
        gatherS<false><<<gg, 256, 0, stream>>>(
            P, PStr, nbp, nStr, outp, oStr, nullptr, 0);
    }
}